// Round 5
// baseline (148.347 us; speedup 1.0000x reference)
//
#include <hip/hip_runtime.h>
#include <hip/hip_bf16.h>
#include <math.h>

// Problem constants
constexpr int Bb = 32;
constexpr int Ll = 1024;
constexpr int DC = 1024;
constexpr int DQ = 1024;
constexpr int Hh = 512;
#define NEG_NUM -10000.0f

typedef __attribute__((ext_vector_type(8))) short bf16x8;
typedef __attribute__((ext_vector_type(4))) float f32x4;

#define GLOAD_LDS16(g, l)                                                  \
    __builtin_amdgcn_global_load_lds(                                      \
        (const __attribute__((address_space(1))) void*)(g),                \
        (__attribute__((address_space(3))) void*)(l), 16, 0, 0)

__device__ inline unsigned short f2bf(float f) {           // RNE f32->bf16
    unsigned int x = __float_as_uint(f);
    unsigned int r = (x + 0x7FFFu + ((x >> 16) & 1u)) >> 16;
    return (unsigned short)r;
}

// ---------------------------------------------------------------------------
// prep, 2432 blocks:
//   [0,2048):    W1[:DC] (1024x512) -> w1t bf16 (512x1024 transposed)
//   [2048,2176): zero out_ctx AND score (32768 floats each)
//   [2176,2432): qb[b,h] = query[b,:] @ W1[DC:,h] + b1[h]
// ---------------------------------------------------------------------------
__global__ __launch_bounds__(256) void prep_kernel(const float* __restrict__ W1,
                                                   const float* __restrict__ query,
                                                   const float* __restrict__ b1,
                                                   unsigned short* __restrict__ w1t,
                                                   float* __restrict__ qb,
                                                   float* __restrict__ score,
                                                   float* __restrict__ out_ctx) {
    __shared__ float red[4][64];
    const int bid = blockIdx.x;
    if (bid < 2048) {
        int idx = bid * 256 + threadIdx.x;   // n*1024 + k
        int n = idx >> 10, k = idx & 1023;
        w1t[idx] = f2bf(W1[(size_t)k * Hh + n]);
    } else if (bid < 2176) {
        int i = (bid - 2048) * 256 + threadIdx.x;
        out_ctx[i] = 0.f;
        score[i] = 0.f;
    } else {
        const int qbid = bid - 2176;          // 0..255
        const int b  = qbid >> 3;
        const int hg = qbid & 7;
        const int hl = threadIdx.x & 63;
        const int j  = threadIdx.x >> 6;
        const int h  = hg * 64 + hl;
        const float* q = query + (size_t)b * DQ + j * 256;
        const float* w = W1 + (size_t)(DC + j * 256) * Hh + h;
        float a0 = 0.f, a1 = 0.f, a2 = 0.f, a3 = 0.f;
#pragma unroll 4
        for (int c = 0; c < 256; c += 4) {
            a0 += q[c + 0] * w[(size_t)(c + 0) * Hh];
            a1 += q[c + 1] * w[(size_t)(c + 1) * Hh];
            a2 += q[c + 2] * w[(size_t)(c + 2) * Hh];
            a3 += q[c + 3] * w[(size_t)(c + 3) * Hh];
        }
        red[j][hl] = (a0 + a1) + (a2 + a3);
        __syncthreads();
        if (j == 0)
            qb[(size_t)b * Hh + h] = red[0][hl] + red[1][hl] + red[2][hl] + red[3][hl] + b1[h];
    }
}

// ---------------------------------------------------------------------------
// Fused cvt + MFMA GEMM + tanh + w2 reduction — m97 shape, reg-staged A.
//   BM=128, BN=128, BK=32, 256 thr / 4 waves (2x2), acc 4x4 per wave.
//   ctx (fp32) -> regs -> cvt -> LDS bf16; w1t via global_load_lds.
//   Per K-step (T3-minimum): issue A loads FIRST, then B gload_lds (so the
//   cvt waits vmcnt(2), B stays in flight), ds_read + 16 MFMA, cvt+ds_write,
//   one __syncthreads (vmcnt(0)+barrier). Both operands double-buffered
//   (32 KB LDS). Score partials via atomicAdd (4 n-blocks/row).
//   Sibling n-blocks (bid + 256k) land on the same XCD (256%8==0) -> A-panel
//   re-reads are L2-local.
// ---------------------------------------------------------------------------
__global__ __launch_bounds__(256) void gemm_fused(const float* __restrict__ ctx,
                                                  const unsigned short* __restrict__ w1t,
                                                  const float* __restrict__ qb,
                                                  const float* __restrict__ w2,
                                                  float* __restrict__ score) {
    __shared__ unsigned short As[2][128 * 32];   // 2 x 8 KB, [m][k] 64B rows
    __shared__ unsigned short Bs[2][128 * 32];   // 2 x 8 KB, [n][k] 64B rows

    const int m0 = blockIdx.x * 128;
    const int n0 = blockIdx.y * 128;
    const int tid = threadIdx.x;
    const int w = tid >> 6, lane = tid & 63;
    const int wr = w >> 1, wc = w & 1;
    const int lr = lane & 15, lk = lane >> 4;
    const int arow = tid >> 1, ahalf = tid & 1;       // A: 2 thr/row, 16 floats each
    const int brow = lane >> 2, bcolb = (lane & 3) * 16;  // B staging within 1KB chunk

    char* AsB = (char*)As;
    char* BsB = (char*)Bs;
    const char* w1tB = (const char*)w1t;

    f32x4 acc[4][4];
#pragma unroll
    for (int mf = 0; mf < 4; ++mf)
#pragma unroll
        for (int nf = 0; nf < 4; ++nf) acc[mf][nf] = (f32x4){0.f, 0.f, 0.f, 0.f};

    // ---- prologue: stage k0 = 0 into buffer 0 ----
    {
        const float* ag = ctx + (size_t)(m0 + arow) * DC + ahalf * 16;
        float4 r0 = *(const float4*)(ag + 0),  r1 = *(const float4*)(ag + 4);
        float4 r2 = *(const float4*)(ag + 8),  r3 = *(const float4*)(ag + 12);
#pragma unroll
        for (int i = 0; i < 2; ++i) {
            int chunk = w * 2 + i;                       // 8 chunks x 1KB = Bs tile
            GLOAD_LDS16(w1tB + (size_t)(n0 + chunk * 16 + brow) * 2048 + bcolb,
                        BsB + chunk * 1024);
        }
        union { unsigned short us[8]; bf16x8 v; } p0, p1;
        p0.us[0] = f2bf(r0.x); p0.us[1] = f2bf(r0.y); p0.us[2] = f2bf(r0.z); p0.us[3] = f2bf(r0.w);
        p0.us[4] = f2bf(r1.x); p0.us[5] = f2bf(r1.y); p0.us[6] = f2bf(r1.z); p0.us[7] = f2bf(r1.w);
        p1.us[0] = f2bf(r2.x); p1.us[1] = f2bf(r2.y); p1.us[2] = f2bf(r2.z); p1.us[3] = f2bf(r2.w);
        p1.us[4] = f2bf(r3.x); p1.us[5] = f2bf(r3.y); p1.us[6] = f2bf(r3.z); p1.us[7] = f2bf(r3.w);
        *(bf16x8*)(AsB + arow * 64 + ahalf * 32 + 0)  = p0.v;
        *(bf16x8*)(AsB + arow * 64 + ahalf * 32 + 16) = p1.v;
    }
    __syncthreads();

    // ---- main loop: 32 K-steps, one barrier each ----
    for (int ks = 0; ks < 32; ++ks) {
        const int cur = ks & 1, nxt = cur ^ 1;
        const bool pf = (ks < 31);
        float4 r0, r1, r2, r3;
        if (pf) {
            const int k1 = (ks + 1) * 32;
            // A fp32 loads FIRST (so cvt's wait leaves B in flight: vmcnt(2))
            const float* ag = ctx + (size_t)(m0 + arow) * DC + k1 + ahalf * 16;
            r0 = *(const float4*)(ag + 0);  r1 = *(const float4*)(ag + 4);
            r2 = *(const float4*)(ag + 8);  r3 = *(const float4*)(ag + 12);
            // B async -> LDS[nxt] (lands during MFMA+cvt window, drains at barrier)
#pragma unroll
            for (int i = 0; i < 2; ++i) {
                int chunk = w * 2 + i;
                GLOAD_LDS16(w1tB + (size_t)(n0 + chunk * 16 + brow) * 2048 + k1 * 2 + bcolb,
                            BsB + nxt * 8192 + chunk * 1024);
            }
        }

        // compute current buffer: 8 ds_read_b128, 16 MFMA
        const char* Ab = AsB + cur * 8192 + (wr * 64 + lr) * 64 + lk * 16;
        const char* Bc = BsB + cur * 8192 + (wc * 64 + lr) * 64 + lk * 16;
        bf16x8 a[4], bb[4];
#pragma unroll
        for (int mf = 0; mf < 4; ++mf) a[mf] = *(const bf16x8*)(Ab + mf * 1024);
#pragma unroll
        for (int nf = 0; nf < 4; ++nf) bb[nf] = *(const bf16x8*)(Bc + nf * 1024);
#pragma unroll
        for (int mf = 0; mf < 4; ++mf)
#pragma unroll
            for (int nf = 0; nf < 4; ++nf)
                acc[mf][nf] = __builtin_amdgcn_mfma_f32_16x16x32_bf16(a[mf], bb[nf], acc[mf][nf], 0, 0, 0);

        if (pf) {
            // cvt + write next A tile (waits only on A loads, B stays in flight)
            union { unsigned short us[8]; bf16x8 v; } p0, p1;
            p0.us[0] = f2bf(r0.x); p0.us[1] = f2bf(r0.y); p0.us[2] = f2bf(r0.z); p0.us[3] = f2bf(r0.w);
            p0.us[4] = f2bf(r1.x); p0.us[5] = f2bf(r1.y); p0.us[6] = f2bf(r1.z); p0.us[7] = f2bf(r1.w);
            p1.us[0] = f2bf(r2.x); p1.us[1] = f2bf(r2.y); p1.us[2] = f2bf(r2.z); p1.us[3] = f2bf(r2.w);
            p1.us[4] = f2bf(r3.x); p1.us[5] = f2bf(r3.y); p1.us[6] = f2bf(r3.z); p1.us[7] = f2bf(r3.w);
            *(bf16x8*)(AsB + nxt * 8192 + arow * 64 + ahalf * 32 + 0)  = p0.v;
            *(bf16x8*)(AsB + nxt * 8192 + arow * 64 + ahalf * 32 + 16) = p1.v;
        }
        __syncthreads();
    }

    // ---- epilogue: score[row] += sum_col tanh(acc + qb[col]) * w2[col] ----
    // C/D layout: col = n0 + wc*64 + nf*16 + lr, row = m0 + wr*64 + mf*16 + lk*4 + r.
    const int bq = m0 >> 10;                     // 128 | 1024 -> one batch per block
    const float* qbb = qb + (size_t)bq * Hh;
#pragma unroll
    for (int mf = 0; mf < 4; ++mf) {
        float s0 = 0.f, s1 = 0.f, s2 = 0.f, s3 = 0.f;
#pragma unroll
        for (int nf = 0; nf < 4; ++nf) {
            int col = n0 + wc * 64 + nf * 16 + lr;
            float wv = w2[col];
            float qv = qbb[col];
            s0 += tanhf(acc[mf][nf][0] + qv) * wv;
            s1 += tanhf(acc[mf][nf][1] + qv) * wv;
            s2 += tanhf(acc[mf][nf][2] + qv) * wv;
            s3 += tanhf(acc[mf][nf][3] + qv) * wv;
        }
#pragma unroll
        for (int off = 8; off; off >>= 1) {
            s0 += __shfl_xor(s0, off, 16);
            s1 += __shfl_xor(s1, off, 16);
            s2 += __shfl_xor(s2, off, 16);
            s3 += __shfl_xor(s3, off, 16);
        }
        if (lr == 0) {
            int row = m0 + wr * 64 + mf * 16 + lk * 4;
            atomicAdd(&score[row + 0], s0);
            atomicAdd(&score[row + 1], s1);
            atomicAdd(&score[row + 2], s2);
            atomicAdd(&score[row + 3], s3);
        }
    }
}

// ---------------------------------------------------------------------------
// scan: p = sigmoid(score + b2, masked, + noise); att_l = p_l * prod_{i<l}(1-p_i)
// ---------------------------------------------------------------------------
__global__ __launch_bounds__(64) void scan_kernel(const float* __restrict__ score,
                                                  const int* __restrict__ mask,
                                                  const float* __restrict__ noise,
                                                  const float* __restrict__ b2p,
                                                  float* __restrict__ att) {
    int b = blockIdx.x;
    int lane = threadIdx.x;
    float b2 = b2p[0];
    int base = b * Ll + lane * 16;

    float p[16], q[16];
    float run = 1.f;
#pragma unroll
    for (int j = 0; j < 16; ++j) {
        int l = base + j;
        float s = score[l] + b2;
        if (mask[l] == 0) s = NEG_NUM;
        s += noise[l];
        float pv = 1.f / (1.f + expf(-s));
        p[j] = pv;
        run *= (1.f - pv);
        q[j] = run;
    }
    float incl = run;
#pragma unroll
    for (int off = 1; off < 64; off <<= 1) {
        float v = __shfl_up(incl, off, 64);
        if (lane >= off) incl *= v;
    }
    float excl = __shfl_up(incl, 1, 64);
    if (lane == 0) excl = 1.f;
#pragma unroll
    for (int j = 0; j < 16; ++j) {
        float P = excl * (j == 0 ? 1.f : q[j - 1]);
        att[base + j] = p[j] * P;
    }
}

// ---------------------------------------------------------------------------
// expected_ctx[b,c] = sum_l att[b,l] * ctx[b,l,c]  (fp32 ctx, float4/thread)
// ---------------------------------------------------------------------------
__global__ __launch_bounds__(256) void ectx_kernel(const float* __restrict__ ctx,
                                                   const float* __restrict__ att,
                                                   float* __restrict__ out) {
    int b = blockIdx.z;
    int c4 = threadIdx.x;                 // c = c4*4
    int l0 = blockIdx.y * 64;
    const float* cb = ctx + ((size_t)b * Ll + l0) * DC + c4 * 4;
    const float* ab = att + (size_t)b * Ll + l0;
    float a0 = 0.f, a1 = 0.f, a2 = 0.f, a3 = 0.f;
#pragma unroll 4
    for (int l = 0; l < 64; ++l) {
        float av = ab[l];
        float4 v = *(const float4*)(cb + (size_t)l * DC);
        a0 += av * v.x; a1 += av * v.y; a2 += av * v.z; a3 += av * v.w;
    }
    float* o = out + (size_t)b * DC + c4 * 4;
    atomicAdd(o + 0, a0); atomicAdd(o + 1, a1);
    atomicAdd(o + 2, a2); atomicAdd(o + 3, a3);
}

// ---------------------------------------------------------------------------
extern "C" void kernel_launch(void* const* d_in, const int* in_sizes, int n_in,
                              void* d_out, int out_size, void* d_ws, size_t ws_size,
                              hipStream_t stream) {
    const float* ctx   = (const float*)d_in[0];
    const float* query = (const float*)d_in[1];
    const int*   mask  = (const int*)d_in[2];
    const float* noise = (const float*)d_in[3];
    const float* W1    = (const float*)d_in[4];
    const float* b1    = (const float*)d_in[5];
    const float* w2    = (const float*)d_in[6];
    const float* b2    = (const float*)d_in[7];

    float* out_ctx = (float*)d_out;                 // [B, DC]
    float* out_att = (float*)d_out + Bb * DC;       // [B, L]

    char* ws = (char*)d_ws;
    float* score = (float*)ws;                                   // 131072 B
    float* qb    = (float*)(ws + 131072);                        //  65536 B
    unsigned short* w1t = (unsigned short*)(ws + 196608);        // 1 MiB
    // total scratch need ~1.25 MB

    // w1t transpose-cvt + zero score/out_ctx + qb (one kernel)
    prep_kernel<<<2432, 256, 0, stream>>>(W1, query, b1, w1t, qb, score, out_ctx);

    // fused cvt+GEMM+tanh+w2 -> score (atomic partials over 4 n-blocks)
    gemm_fused<<<dim3((Bb * Ll) / 128, Hh / 128), 256, 0, stream>>>(ctx, w1t, qb, w2, score);

    // sigmoid/mask/noise/scan -> att (second output)
    scan_kernel<<<Bb, 64, 0, stream>>>(score, mask, noise, b2, out_att);

    // expected_ctx = att @ ctx (fp32 ctx, largely L3-resident after gemm)
    ectx_kernel<<<dim3(1, Ll / 64, Bb), 256, 0, stream>>>(ctx, out_att, out_ctx);
}

// Round 6
// 132.522 us; speedup vs baseline: 1.1194x; 1.1194x over previous
//
#include <hip/hip_runtime.h>
#include <hip/hip_bf16.h>
#include <math.h>

// Problem constants
constexpr int Bb = 32;
constexpr int Ll = 1024;
constexpr int DC = 1024;
constexpr int DQ = 1024;
constexpr int Hh = 512;
#define NEG_NUM -10000.0f

typedef __attribute__((ext_vector_type(8))) short bf16x8;
typedef __attribute__((ext_vector_type(4))) float f32x4;

#define GLOAD_LDS16(g, l)                                                  \
    __builtin_amdgcn_global_load_lds(                                      \
        (const __attribute__((address_space(1))) void*)(g),                \
        (__attribute__((address_space(3))) void*)(l), 16, 0, 0)

__device__ inline unsigned short f2bf(float f) {           // RNE f32->bf16
    unsigned int x = __float_as_uint(f);
    unsigned int r = (x + 0x7FFFu + ((x >> 16) & 1u)) >> 16;
    return (unsigned short)r;
}

// ---------------------------------------------------------------------------
// prep, 2432 blocks:
//   [0,2048):    W1[:DC] (1024x512) -> w1t bf16 (512x1024 transposed)
//   [2048,2176): zero out_ctx AND score (32768 floats each)
//   [2176,2432): qb[b,h] = query[b,:] @ W1[DC:,h] + b1[h]
// ---------------------------------------------------------------------------
__global__ __launch_bounds__(256) void prep_kernel(const float* __restrict__ W1,
                                                   const float* __restrict__ query,
                                                   const float* __restrict__ b1,
                                                   unsigned short* __restrict__ w1t,
                                                   float* __restrict__ qb,
                                                   float* __restrict__ score,
                                                   float* __restrict__ out_ctx) {
    __shared__ float red[4][64];
    const int bid = blockIdx.x;
    if (bid < 2048) {
        int idx = bid * 256 + threadIdx.x;   // n*1024 + k
        int n = idx >> 10, k = idx & 1023;
        w1t[idx] = f2bf(W1[(size_t)k * Hh + n]);
    } else if (bid < 2176) {
        int i = (bid - 2048) * 256 + threadIdx.x;
        out_ctx[i] = 0.f;
        score[i] = 0.f;
    } else {
        const int qbid = bid - 2176;          // 0..255
        const int b  = qbid >> 3;
        const int hg = qbid & 7;
        const int hl = threadIdx.x & 63;
        const int j  = threadIdx.x >> 6;
        const int h  = hg * 64 + hl;
        const float* q = query + (size_t)b * DQ + j * 256;
        const float* w = W1 + (size_t)(DC + j * 256) * Hh + h;
        float a0 = 0.f, a1 = 0.f, a2 = 0.f, a3 = 0.f;
#pragma unroll 4
        for (int c = 0; c < 256; c += 4) {
            a0 += q[c + 0] * w[(size_t)(c + 0) * Hh];
            a1 += q[c + 1] * w[(size_t)(c + 1) * Hh];
            a2 += q[c + 2] * w[(size_t)(c + 2) * Hh];
            a3 += q[c + 3] * w[(size_t)(c + 3) * Hh];
        }
        red[j][hl] = (a0 + a1) + (a2 + a3);
        __syncthreads();
        if (j == 0)
            qb[(size_t)b * Hh + h] = red[0][hl] + red[1][hl] + red[2][hl] + red[3][hl] + b1[h];
    }
}

// ---------------------------------------------------------------------------
// Fused MFMA GEMM + tanh + w2 reduction — m97 schedule, fp32-A-in-LDS.
//   BM=128, BN=128, BK=32, 256 thr / 4 waves (2x2), acc 4x4 per wave.
//   ALL staging via fire-and-forget global_load_lds (never blocks the wave):
//     A: raw fp32, 16 KB/step, [row][128B] linear dest; source pre-XOR'd by
//        ((row&7)<<4) so an XOR on the ds_read restores linear data with the
//        bank-conflict floor (rule 21: linear dest + inv-swz source + swz read).
//     B: bf16 w1t, 8 KB/step (byte-identical to the R2-verified path).
//   Single buffer, 2 barriers/step (m97 proven loop). Cvt fp32->bf16 happens
//   on the LDS->reg fragment read (3 int-ops/elem, overlapped with MFMA).
//   This deletes the standalone 201 MB cvt pass entirely.
// ---------------------------------------------------------------------------
__global__ __launch_bounds__(256) void gemm_fused(const float* __restrict__ ctx,
                                                  const unsigned short* __restrict__ w1t,
                                                  const float* __restrict__ qb,
                                                  const float* __restrict__ w2,
                                                  float* __restrict__ score) {
    __shared__ float As[128 * 32];           // fp32 [m][32 floats] = 16 KB
    __shared__ unsigned short Bs[128 * 32];  // bf16 [n][64B]       =  8 KB
    __shared__ float red4[4][64];

    const int m0 = blockIdx.x * 128;
    const int n0 = blockIdx.y * 128;
    const int tid = threadIdx.x;
    const int w = tid >> 6, lane = tid & 63;
    const int wr = w >> 1, wc = w & 1;
    const int lr = lane & 15, lk = lane >> 4;

    const char* ctxB = (const char*)ctx;
    const char* w1tB = (const char*)w1t;
    char* AsB = (char*)As;
    char* BsB = (char*)Bs;

    // A staging: round r covers rows r*32 + w*8 + (lane>>3); lane's 16B slot
    // within the 128B row is ((lane&7)*16) ^ ((row&7)<<4)  [row&7 == lane>>3]
    const int arow8 = lane >> 3;                       // 0..7
    const int acol  = ((lane & 7) * 16) ^ (arow8 << 4);

    f32x4 acc[4][4];
#pragma unroll
    for (int mf = 0; mf < 4; ++mf)
#pragma unroll
        for (int nf = 0; nf < 4; ++nf) acc[mf][nf] = (f32x4){0.f, 0.f, 0.f, 0.f};

    for (int k0 = 0; k0 < DC; k0 += 32) {
        // ---- stage (fire-and-forget) ----
#pragma unroll
        for (int r = 0; r < 4; ++r) {
            int row = r * 32 + w * 8 + arow8;
            GLOAD_LDS16(ctxB + (size_t)(m0 + row) * 4096 + k0 * 4 + acol,
                        AsB + r * 4096 + w * 1024);
        }
#pragma unroll
        for (int i = 0; i < 2; ++i) {
            int cbyte = w * 2048 + i * 1024;
            int c = cbyte + lane * 16;
            int row = c >> 6, colb = c & 63;
            GLOAD_LDS16(w1tB + (size_t)(n0 + row) * 2048 + k0 * 2 + colb,
                        BsB + cbyte);
        }
        __syncthreads();

        // ---- fragments: A fp32 (2x b128, XOR'd addr) -> cvt bf16x8 ----
        bf16x8 a[4], bb[4];
#pragma unroll
        for (int mf = 0; mf < 4; ++mf) {
            int arow = wr * 64 + mf * 16 + lr;
            int base = arow * 128 + lk * 32;
            int x = (lr & 7) << 4;
            float4 f0 = *(const float4*)(AsB + ((base +  0) ^ x));
            float4 f1 = *(const float4*)(AsB + ((base + 16) ^ x));
            union { unsigned short us[8]; bf16x8 v; } pk;
            pk.us[0] = f2bf(f0.x); pk.us[1] = f2bf(f0.y);
            pk.us[2] = f2bf(f0.z); pk.us[3] = f2bf(f0.w);
            pk.us[4] = f2bf(f1.x); pk.us[5] = f2bf(f1.y);
            pk.us[6] = f2bf(f1.z); pk.us[7] = f2bf(f1.w);
            a[mf] = pk.v;
        }
#pragma unroll
        for (int nf = 0; nf < 4; ++nf)
            bb[nf] = *(const bf16x8*)(BsB + (wc * 64 + nf * 16 + lr) * 64 + lk * 16);

#pragma unroll
        for (int mf = 0; mf < 4; ++mf)
#pragma unroll
            for (int nf = 0; nf < 4; ++nf)
                acc[mf][nf] = __builtin_amdgcn_mfma_f32_16x16x32_bf16(a[mf], bb[nf], acc[mf][nf], 0, 0, 0);
        __syncthreads();
    }

    // ---- epilogue: score[row] += sum_col tanh(acc + qb[col]) * w2[col] ----
    // C/D layout: col = n0 + wc*64 + nf*16 + lr, row = m0 + wr*64 + mf*16 + lk*4 + r.
    const int bq = m0 >> 10;                     // 128 | 1024 -> one batch per block
    const float* qbb = qb + (size_t)bq * Hh;
#pragma unroll
    for (int mf = 0; mf < 4; ++mf) {
        float s0 = 0.f, s1 = 0.f, s2 = 0.f, s3 = 0.f;
#pragma unroll
        for (int nf = 0; nf < 4; ++nf) {
            int col = n0 + wc * 64 + nf * 16 + lr;
            float wv = w2[col];
            float qv = qbb[col];
            s0 += tanhf(acc[mf][nf][0] + qv) * wv;
            s1 += tanhf(acc[mf][nf][1] + qv) * wv;
            s2 += tanhf(acc[mf][nf][2] + qv) * wv;
            s3 += tanhf(acc[mf][nf][3] + qv) * wv;
        }
#pragma unroll
        for (int off = 8; off; off >>= 1) {
            s0 += __shfl_xor(s0, off, 16);
            s1 += __shfl_xor(s1, off, 16);
            s2 += __shfl_xor(s2, off, 16);
            s3 += __shfl_xor(s3, off, 16);
        }
        if (lr == 0) {
            int row = m0 + wr * 64 + mf * 16 + lk * 4;
            atomicAdd(&score[row + 0], s0);
            atomicAdd(&score[row + 1], s1);
            atomicAdd(&score[row + 2], s2);
            atomicAdd(&score[row + 3], s3);
        }
    }
    (void)red4;
}

// ---------------------------------------------------------------------------
// scan: p = sigmoid(score + b2, masked, + noise); att_l = p_l * prod_{i<l}(1-p_i)
// ---------------------------------------------------------------------------
__global__ __launch_bounds__(64) void scan_kernel(const float* __restrict__ score,
                                                  const int* __restrict__ mask,
                                                  const float* __restrict__ noise,
                                                  const float* __restrict__ b2p,
                                                  float* __restrict__ att) {
    int b = blockIdx.x;
    int lane = threadIdx.x;
    float b2 = b2p[0];
    int base = b * Ll + lane * 16;

    float p[16], q[16];
    float run = 1.f;
#pragma unroll
    for (int j = 0; j < 16; ++j) {
        int l = base + j;
        float s = score[l] + b2;
        if (mask[l] == 0) s = NEG_NUM;
        s += noise[l];
        float pv = 1.f / (1.f + expf(-s));
        p[j] = pv;
        run *= (1.f - pv);
        q[j] = run;
    }
    float incl = run;
#pragma unroll
    for (int off = 1; off < 64; off <<= 1) {
        float v = __shfl_up(incl, off, 64);
        if (lane >= off) incl *= v;
    }
    float excl = __shfl_up(incl, 1, 64);
    if (lane == 0) excl = 1.f;
#pragma unroll
    for (int j = 0; j < 16; ++j) {
        float P = excl * (j == 0 ? 1.f : q[j - 1]);
        att[base + j] = p[j] * P;
    }
}

// ---------------------------------------------------------------------------
// expected_ctx[b,c] = sum_l att[b,l] * ctx[b,l,c]  (fp32 ctx, float4/thread)
// ---------------------------------------------------------------------------
__global__ __launch_bounds__(256) void ectx_kernel(const float* __restrict__ ctx,
                                                   const float* __restrict__ att,
                                                   float* __restrict__ out) {
    int b = blockIdx.z;
    int c4 = threadIdx.x;                 // c = c4*4
    int l0 = blockIdx.y * 64;
    const float* cb = ctx + ((size_t)b * Ll + l0) * DC + c4 * 4;
    const float* ab = att + (size_t)b * Ll + l0;
    float a0 = 0.f, a1 = 0.f, a2 = 0.f, a3 = 0.f;
#pragma unroll 4
    for (int l = 0; l < 64; ++l) {
        float av = ab[l];
        float4 v = *(const float4*)(cb + (size_t)l * DC);
        a0 += av * v.x; a1 += av * v.y; a2 += av * v.z; a3 += av * v.w;
    }
    float* o = out + (size_t)b * DC + c4 * 4;
    atomicAdd(o + 0, a0); atomicAdd(o + 1, a1);
    atomicAdd(o + 2, a2); atomicAdd(o + 3, a3);
}

// ---------------------------------------------------------------------------
extern "C" void kernel_launch(void* const* d_in, const int* in_sizes, int n_in,
                              void* d_out, int out_size, void* d_ws, size_t ws_size,
                              hipStream_t stream) {
    const float* ctx   = (const float*)d_in[0];
    const float* query = (const float*)d_in[1];
    const int*   mask  = (const int*)d_in[2];
    const float* noise = (const float*)d_in[3];
    const float* W1    = (const float*)d_in[4];
    const float* b1    = (const float*)d_in[5];
    const float* w2    = (const float*)d_in[6];
    const float* b2    = (const float*)d_in[7];

    float* out_ctx = (float*)d_out;                 // [B, DC]
    float* out_att = (float*)d_out + Bb * DC;       // [B, L]

    char* ws = (char*)d_ws;
    float* score = (float*)ws;                                   // 131072 B
    float* qb    = (float*)(ws + 131072);                        //  65536 B
    unsigned short* w1t = (unsigned short*)(ws + 196608);        // 1 MiB
    // total scratch need ~1.25 MB

    // w1t transpose-cvt + zero score/out_ctx + qb (one kernel)
    prep_kernel<<<2432, 256, 0, stream>>>(W1, query, b1, w1t, qb, score, out_ctx);

    // fused GEMM (fp32-A staged, cvt on read) + tanh + w2 -> score
    gemm_fused<<<dim3((Bb * Ll) / 128, Hh / 128), 256, 0, stream>>>(ctx, w1t, qb, w2, score);

    // sigmoid/mask/noise/scan -> att (second output)
    scan_kernel<<<Bb, 64, 0, stream>>>(score, mask, noise, b2, out_att);

    // expected_ctx = att @ ctx (fp32 ctx, largely L3-resident after gemm)
    ectx_kernel<<<dim3(1, Ll / 64, Bb), 256, 0, stream>>>(ctx, out_att, out_ctx);
}